// Round 3
// baseline (23531.927 us; speedup 1.0000x reference)
//
#include <hip/hip_runtime.h>
#include <hip/hip_fp16.h>
#include <math.h>

// Problem constants
#define BATCH 256
#define TSEQ  512
#define FEAT  64
#define NU1   256
#define NU2   128
#define ROWS  2      // batch rows per WG -> 128 WGs

// Packed fp16 weight planes in d_ws, quad-group layout:
//   element index ((quad*COLS + col)*4 + i)  (in __half2 units)
// A "quad" = 4 row-pairs = 8 consecutive K-rows of one column; one 16B load.
// GRU1: K-space 320 rows (64 x-rows then 256 h-rows) -> 160 pairs -> 40 quads, 256 cols.
// GRU2: K-space 384 rows (256 h1-rows then 128 h2-rows) -> 192 pairs -> 48 quads, 128 cols.
#define G1Z_OFF 0
#define G1R_OFF 40960
#define G1H_OFF 81920
#define G2Z_OFF 122880
#define G2R_OFF 147456
#define G2H_OFF 172032
#define TOTAL_H2 196608   // 786,432 bytes of d_ws

__device__ __forceinline__ float sigmoid_f(float v) {
    return 1.0f / (1.0f + __expf(-v));
}
__device__ __forceinline__ float tanh_f(float v) {
    float c = fminf(fmaxf(v, -15.0f), 15.0f);
    float e = __expf(2.0f * c);
    return (e - 1.0f) / (e + 1.0f);
}

// ---------------- weight packing (fp32 -> fp16 quad planes) ----------------
__global__ void pack_weights(const float* __restrict__ k1, const float* __restrict__ r1,
                             const float* __restrict__ k2, const float* __restrict__ r2,
                             __half2* __restrict__ ws)
{
    int idx = blockIdx.x * 256 + threadIdx.x;
    if (idx >= TOTAL_H2) return;
    float a, b;
    if (idx < G2Z_OFF) {
        // GRU1 planes: 3 x [40 quads][256 cols][4]
        int plane = idx / 40960;        // 0=z 1=r 2=h
        int rem   = idx % 40960;
        int quad  = rem >> 10;          // /1024
        int c4    = rem & 1023;
        int col   = c4 >> 2;
        int i     = c4 & 3;
        int g     = plane * 256 + col;  // gate-column in [0,768)
        int row0  = (quad * 4 + i) * 2; // K-row (0..318 even)
        if (row0 < 64) { a = k1[row0 * 768 + g];        b = k1[(row0 + 1) * 768 + g]; }
        else           { a = r1[(row0 - 64) * 768 + g]; b = r1[(row0 - 63) * 768 + g]; }
    } else {
        // GRU2 planes: 3 x [48 quads][128 cols][4]
        int idx2  = idx - G2Z_OFF;
        int plane = idx2 / 24576;
        int rem   = idx2 % 24576;
        int quad  = rem >> 9;           // /512
        int c4    = rem & 511;
        int col   = c4 >> 2;
        int i     = c4 & 3;
        int g     = plane * 128 + col;  // gate-column in [0,384)
        int row0  = (quad * 4 + i) * 2; // K-row (0..382 even)
        if (row0 < 256) { a = k2[row0 * 384 + g];         b = k2[(row0 + 1) * 384 + g]; }
        else            { a = r2[(row0 - 256) * 384 + g]; b = r2[(row0 - 255) * 384 + g]; }
    }
    __half2 h;
    h.x = __float2half_rn(a);
    h.y = __float2half_rn(b);
    ws[idx] = h;
}

// acc += w.lo * x0 + w.hi * x1  (fp16 weight, fp32 data/accum)
__device__ __forceinline__ void fma2(float& acc, __half2 w, float x0, float x1) {
    acc = fmaf(__half2float(__low2half(w)),  x0, acc);
    acc = fmaf(__half2float(__high2half(w)), x1, acc);
}
// one quad (8 K-rows) of one gate against 8 input floats
__device__ __forceinline__ void fmaq(float& acc, float4 wf, const float4& a, const float4& b) {
    union { float4 f; __half2 h[4]; } w; w.f = wf;
    fma2(acc, w.h[0], a.x, a.y); fma2(acc, w.h[1], a.z, a.w);
    fma2(acc, w.h[2], b.x, b.y); fma2(acc, w.h[3], b.z, b.w);
}

// Two-row K-segment: NQ quads, double-buffered in blocks of 2 quads
// (6 dwordx4 loads in flight while 96 fp16 MACs retire).
template <int COLS, int NQ>
__device__ __forceinline__ void segq2(const __half2* __restrict__ pz,
                                      const __half2* __restrict__ pr,
                                      const __half2* __restrict__ ph,
                                      const float* __restrict__ s0,
                                      const float* __restrict__ s1,
                                      float (&az)[2], float (&ar)[2], float (&a3)[2])
{
    constexpr int QB = 2;
    constexpr int NB = NQ / QB;
    float4 wz[2][QB], wr[2][QB], wh[2][QB];
    #pragma unroll
    for (int q = 0; q < QB; ++q) {
        wz[0][q] = *(const float4*)(pz + q * COLS * 4);
        wr[0][q] = *(const float4*)(pr + q * COLS * 4);
        wh[0][q] = *(const float4*)(ph + q * COLS * 4);
    }
    #pragma unroll
    for (int b = 0; b < NB; ++b) {
        const int cur = b & 1, nxt = cur ^ 1;
        if (b + 1 < NB) {
            #pragma unroll
            for (int q = 0; q < QB; ++q) {
                const int qq = (b + 1) * QB + q;
                wz[nxt][q] = *(const float4*)(pz + qq * COLS * 4);
                wr[nxt][q] = *(const float4*)(pr + qq * COLS * 4);
                wh[nxt][q] = *(const float4*)(ph + qq * COLS * 4);
            }
        }
        #pragma unroll
        for (int q = 0; q < QB; ++q) {
            const int k0 = (b * QB + q) * 8;
            const float4 a0 = *(const float4*)(s0 + k0);
            const float4 b0 = *(const float4*)(s0 + k0 + 4);
            const float4 a1 = *(const float4*)(s1 + k0);
            const float4 b1 = *(const float4*)(s1 + k0 + 4);
            fmaq(az[0], wz[cur][q], a0, b0); fmaq(az[1], wz[cur][q], a1, b1);
            fmaq(ar[0], wr[cur][q], a0, b0); fmaq(ar[1], wr[cur][q], a1, b1);
            fmaq(a3[0], wh[cur][q], a0, b0); fmaq(a3[1], wh[cur][q], a1, b1);
        }
    }
}

// Single-row K-segment
template <int COLS, int NQ>
__device__ __forceinline__ void segq1(const __half2* __restrict__ pz,
                                      const __half2* __restrict__ pr,
                                      const __half2* __restrict__ ph,
                                      const float* __restrict__ s0,
                                      float& az, float& ar, float& a3)
{
    constexpr int QB = 2;
    constexpr int NB = NQ / QB;
    float4 wz[2][QB], wr[2][QB], wh[2][QB];
    #pragma unroll
    for (int q = 0; q < QB; ++q) {
        wz[0][q] = *(const float4*)(pz + q * COLS * 4);
        wr[0][q] = *(const float4*)(pr + q * COLS * 4);
        wh[0][q] = *(const float4*)(ph + q * COLS * 4);
    }
    #pragma unroll
    for (int b = 0; b < NB; ++b) {
        const int cur = b & 1, nxt = cur ^ 1;
        if (b + 1 < NB) {
            #pragma unroll
            for (int q = 0; q < QB; ++q) {
                const int qq = (b + 1) * QB + q;
                wz[nxt][q] = *(const float4*)(pz + qq * COLS * 4);
                wr[nxt][q] = *(const float4*)(pr + qq * COLS * 4);
                wh[nxt][q] = *(const float4*)(ph + qq * COLS * 4);
            }
        }
        #pragma unroll
        for (int q = 0; q < QB; ++q) {
            const int k0 = (b * QB + q) * 8;
            const float4 a0 = *(const float4*)(s0 + k0);
            const float4 b0 = *(const float4*)(s0 + k0 + 4);
            fmaq(az, wz[cur][q], a0, b0);
            fmaq(ar, wr[cur][q], a0, b0);
            fmaq(a3, wh[cur][q], a0, b0);
        }
    }
}

// 512 threads: col j = tid&255, K-half hf = tid>>8. 2 waves/SIMD.
__global__ __launch_bounds__(512, 2)
void gru_fused(const float* __restrict__ x,
               const float* __restrict__ b1, const float* __restrict__ b2,
               const float* __restrict__ w3, const float* __restrict__ b3,
               const float* __restrict__ w4, const float* __restrict__ b4,
               const float* __restrict__ w5, const float* __restrict__ b5,
               const __half2* __restrict__ wp,
               float* __restrict__ out)
{
    __shared__ float h1[ROWS][NU1];
    __shared__ float h2[ROWS][NU2];
    __shared__ float xt[2][ROWS][FEAT];
    __shared__ float red1[6][256];
    __shared__ float red2[4][256];
    __shared__ float d3[ROWS][64];
    __shared__ float d4[ROWS][32];

    const int tid  = threadIdx.x;
    const int j    = tid & 255;     // output column (GRU1 unit)
    const int hf   = tid >> 8;      // K-half
    const int row0 = blockIdx.x * ROWS;
    const int u2   = j & 127;       // GRU2 unit
    const int rr   = j >> 7;        // GRU2 batch row

    for (int i = tid; i < ROWS * NU1; i += 512) (&h1[0][0])[i] = 0.0f;
    for (int i = tid; i < ROWS * NU2; i += 512) (&h2[0][0])[i] = 0.0f;

    // biases only on the combining half (hf==0); hf==1 accumulates raw partials
    float bz1 = 0, br1 = 0, bxh1 = 0, brh1 = 0;
    float bz2 = 0, br2 = 0, bxh2 = 0, brh2 = 0;
    if (hf == 0) {
        bz1  = b1[j] + b1[768 + j];
        br1  = b1[256 + j] + b1[1024 + j];
        bxh1 = b1[512 + j];
        brh1 = b1[1280 + j];
        bz2  = b2[u2] + b2[384 + u2];
        br2  = b2[128 + u2] + b2[512 + u2];
        bxh2 = b2[256 + u2];
        brh2 = b2[640 + u2];
    }

    const __half2* g1z = wp + G1Z_OFF + j * 4;
    const __half2* g1r = wp + G1R_OFF + j * 4;
    const __half2* g1h = wp + G1H_OFF + j * 4;
    const __half2* g2z = wp + G2Z_OFF + u2 * 4;
    const __half2* g2r = wp + G2R_OFF + u2 * 4;
    const __half2* g2h = wp + G2H_OFF + u2 * 4;

    const int pr_ = tid >> 6, pf = tid & 63;   // x-stager (tid<128)
    if (tid < ROWS * FEAT)
        xt[0][pr_][pf] = x[((size_t)(row0 + pr_) * TSEQ) * FEAT + pf];
    __syncthreads();

    for (int t = 0; t < TSEQ; ++t) {
        const int cur = t & 1, nxt = cur ^ 1;

        float xpre = 0.0f;
        if (t + 1 < TSEQ && tid < ROWS * FEAT)
            xpre = x[((size_t)(row0 + pr_) * TSEQ + (t + 1)) * FEAT + pf];

        // ---------------- GRU1: partials over K-half ----------------
        float az[2]  = {bz1, bz1},  ar[2]  = {br1, br1};
        float axh[2] = {bxh1, bxh1}, arh[2] = {brh1, brh1};
        if (hf == 0) {
            // quads 0..7: x-part (K rows 0..63) -> axh
            segq2<256, 8>(g1z, g1r, g1h,
                          &xt[cur][0][0], &xt[cur][1][0], az, ar, axh);
            // quads 8..19: h-part rows 0..95 -> arh
            segq2<256, 12>(g1z + 8 * 1024, g1r + 8 * 1024, g1h + 8 * 1024,
                           &h1[0][0], &h1[1][0], az, ar, arh);
        } else {
            // quads 20..39: h-part rows 96..255 -> arh
            segq2<256, 20>(g1z + 20 * 1024, g1r + 20 * 1024, g1h + 20 * 1024,
                           &h1[0][96], &h1[1][96], az, ar, arh);
        }
        if (hf == 1) {
            red1[0][j] = az[0];  red1[1][j] = az[1];
            red1[2][j] = ar[0];  red1[3][j] = ar[1];
            red1[4][j] = arh[0]; red1[5][j] = arh[1];
        }
        __syncthreads();   // (A) partials stored; all reads of old h1/xt done
        if (hf == 0) {
            az[0]  += red1[0][j]; az[1]  += red1[1][j];
            ar[0]  += red1[2][j]; ar[1]  += red1[3][j];
            arh[0] += red1[4][j]; arh[1] += red1[5][j];
            #pragma unroll
            for (int r = 0; r < 2; ++r) {
                const float z  = sigmoid_f(az[r]);
                const float rg = sigmoid_f(ar[r]);
                const float hh = tanh_f(axh[r] + rg * arh[r]);
                h1[r][j] = z * h1[r][j] + (1.0f - z) * hh;
            }
        }
        if (t + 1 < TSEQ && tid < ROWS * FEAT) xt[nxt][pr_][pf] = xpre;
        __syncthreads();   // (B) new h1 + next x visible

        // ---------------- GRU2: partials over K-half ----------------
        float az2 = bz2, ar2 = br2, axh2 = bxh2, arh2 = brh2;
        if (hf == 0) {
            // quads 0..23: h1 rows 0..191 -> axh2
            segq1<128, 24>(g2z, g2r, g2h, &h1[rr][0], az2, ar2, axh2);
        } else {
            // quads 24..31: h1 rows 192..255 -> axh2
            segq1<128, 8>(g2z + 24 * 512, g2r + 24 * 512, g2h + 24 * 512,
                          &h1[rr][192], az2, ar2, axh2);
            // quads 32..47: h2 rows 0..127 -> arh2
            segq1<128, 16>(g2z + 32 * 512, g2r + 32 * 512, g2h + 32 * 512,
                           &h2[rr][0], az2, ar2, arh2);
        }
        if (hf == 1) {
            red2[0][j] = az2; red2[1][j] = ar2;
            red2[2][j] = axh2; red2[3][j] = arh2;
        }
        __syncthreads();   // (C) partials stored; all reads of old h2 done
        if (hf == 0) {
            az2  += red2[0][j]; ar2  += red2[1][j];
            axh2 += red2[2][j]; arh2 += red2[3][j];
            const float z2v = sigmoid_f(az2);
            const float rg2 = sigmoid_f(ar2);
            const float hh2 = tanh_f(axh2 + rg2 * arh2);
            h2[rr][u2] = z2v * h2[rr][u2] + (1.0f - z2v) * hh2;
        }
        __syncthreads();   // (D) new h2 visible
    }

    // ---------------- dense head: h2 -> 64 -> 32 -> 24 ----------------
    if (tid < ROWS * 64) {
        const int r = tid >> 6, jj = tid & 63;
        float a = b3[jj];
        #pragma unroll 4
        for (int u = 0; u < NU2; ++u) a += h2[r][u] * w3[u * 64 + jj];
        d3[r][jj] = a;
    }
    __syncthreads();
    if (tid < ROWS * 32) {
        const int r = tid >> 5, jj = tid & 31;
        float a = b4[jj];
        #pragma unroll 4
        for (int u = 0; u < 64; ++u) a += d3[r][u] * w4[u * 32 + jj];
        d4[r][jj] = a;
    }
    __syncthreads();
    if (tid < ROWS * 32) {
        const int r = tid >> 5, jj = tid & 31;
        if (jj < 24) {
            float a = b5[jj];
            #pragma unroll 4
            for (int u = 0; u < 32; ++u) a += d4[r][u] * w5[u * 24 + jj];
            out[(size_t)(row0 + r) * 24 + jj] = a;
        }
    }
}

extern "C" void kernel_launch(void* const* d_in, const int* in_sizes, int n_in,
                              void* d_out, int out_size, void* d_ws, size_t ws_size,
                              hipStream_t stream) {
    (void)in_sizes; (void)n_in; (void)ws_size; (void)out_size;
    const float* x  = (const float*)d_in[0];
    const float* k1 = (const float*)d_in[1];
    const float* r1 = (const float*)d_in[2];
    const float* b1 = (const float*)d_in[3];
    const float* k2 = (const float*)d_in[4];
    const float* r2 = (const float*)d_in[5];
    const float* b2 = (const float*)d_in[6];
    const float* w3 = (const float*)d_in[7];
    const float* b3 = (const float*)d_in[8];
    const float* w4 = (const float*)d_in[9];
    const float* b4 = (const float*)d_in[10];
    const float* w5 = (const float*)d_in[11];
    const float* b5 = (const float*)d_in[12];
    float* out = (float*)d_out;
    __half2* wp = (__half2*)d_ws;

    hipLaunchKernelGGL(pack_weights, dim3((TOTAL_H2 + 255) / 256), dim3(256), 0, stream,
                       k1, r1, k2, r2, wp);
    hipLaunchKernelGGL(gru_fused, dim3(BATCH / ROWS), dim3(512), 0, stream,
                       x, b1, b2, w3, b3, w4, b4, w5, b5, wp, out);
}

// Round 4
// 9591.696 us; speedup vs baseline: 2.4534x; 2.4534x over previous
//
#include <hip/hip_runtime.h>
#include <hip/hip_fp16.h>
#include <math.h>

// Problem constants
#define BATCH 256
#define TSEQ  512
#define FEAT  64
#define NU1   256
#define NU2   128
#define ROWS  2      // batch rows per WG -> 128 WGs
#define BLK   8      // pairs per pipeline block (24 outstanding 4B loads)

// half2-element offsets inside workspace (packed fp16 weight planes)
// Pair-plane layout (R2-proven, L2-resident): plane[pair][col], half2=(row0,row0+1).
// GRU1: 160 pairs (64 x-rows then 256 h-rows) x 256 cols, per gate.
// GRU2: 192 pairs (256 h1-rows then 128 h2-rows) x 128 cols, per gate.
#define G1Z_OFF 0
#define G1R_OFF 40960
#define G1H_OFF 81920
#define G2Z_OFF 122880
#define G2R_OFF 147456
#define G2H_OFF 172032
#define TOTAL_H2 196608   // 786,432 bytes of d_ws

__device__ __forceinline__ float sigmoid_f(float v) {
    return 1.0f / (1.0f + __expf(-v));
}
__device__ __forceinline__ float tanh_f(float v) {
    float c = fminf(fmaxf(v, -15.0f), 15.0f);
    float e = __expf(2.0f * c);
    return (e - 1.0f) / (e + 1.0f);
}

// ---------------- weight packing (fp32 -> fp16 pair planes) ----------------
__global__ void pack_weights(const float* __restrict__ k1, const float* __restrict__ r1,
                             const float* __restrict__ k2, const float* __restrict__ r2,
                             __half2* __restrict__ ws)
{
    int idx = blockIdx.x * 256 + threadIdx.x;
    if (idx >= TOTAL_H2) return;
    float a, b;
    if (idx < G2Z_OFF) {
        // GRU1 planes: 3 x [160 pairs][256 cols]
        int plane = idx / 40960;       // 0=z 1=r 2=h
        int rem   = idx % 40960;
        int pair  = rem >> 8;
        int col   = rem & 255;
        int g     = plane * 256 + col; // gate-column in [0,768)
        int row0  = pair * 2;
        if (row0 < 64) { a = k1[row0 * 768 + g];        b = k1[(row0 + 1) * 768 + g]; }
        else           { a = r1[(row0 - 64) * 768 + g]; b = r1[(row0 - 63) * 768 + g]; }
    } else {
        // GRU2 planes: 3 x [192 pairs][128 cols]
        int idx2  = idx - G2Z_OFF;
        int plane = idx2 / 24576;
        int rem   = idx2 % 24576;
        int pair  = rem >> 7;
        int col   = rem & 127;
        int g     = plane * 128 + col; // gate-column in [0,384)
        int row0  = pair * 2;
        if (row0 < 256) { a = k2[row0 * 384 + g];         b = k2[(row0 + 1) * 384 + g]; }
        else            { a = r2[(row0 - 256) * 384 + g]; b = r2[(row0 - 255) * 384 + g]; }
    }
    __half2 h;
    h.x = __float2half_rn(a);
    h.y = __float2half_rn(b);
    ws[idx] = h;
}

// acc += w.lo * x0 + w.hi * x1   (fp16 weight, fp32 data/accum; cvt is exact)
__device__ __forceinline__ void fma2(float& acc, __half2 w, float x0, float x1) {
    acc = fmaf(__half2float(__low2half(w)),  x0, acc);
    acc = fmaf(__half2float(__high2half(w)), x1, acc);
}

// Two-batch-row segment over NPAIRS K-pairs (4B loads, stride COLS half2).
template <int COLS, int NPAIRS>
__device__ __forceinline__ void gru_seg2(const __half2* __restrict__ pz,
                                         const __half2* __restrict__ pr,
                                         const __half2* __restrict__ ph,
                                         const float* __restrict__ s0,
                                         const float* __restrict__ s1,
                                         float (&az)[2], float (&ar)[2], float (&a3)[2])
{
    constexpr int NB = NPAIRS / BLK;
    __half2 bz[2][BLK], br[2][BLK], bh[2][BLK];
    #pragma unroll
    for (int q = 0; q < BLK; ++q) {
        bz[0][q] = pz[q * COLS]; br[0][q] = pr[q * COLS]; bh[0][q] = ph[q * COLS];
    }
    #pragma unroll 2
    for (int b = 0; b < NB; ++b) {
        const int cur = b & 1, nxt = cur ^ 1;
        if (b + 1 < NB) {
            const __half2* z2 = pz + (b + 1) * BLK * COLS;
            const __half2* r2 = pr + (b + 1) * BLK * COLS;
            const __half2* h2 = ph + (b + 1) * BLK * COLS;
            #pragma unroll
            for (int q = 0; q < BLK; ++q) {
                bz[nxt][q] = z2[q * COLS]; br[nxt][q] = r2[q * COLS]; bh[nxt][q] = h2[q * COLS];
            }
        }
        #pragma unroll
        for (int q = 0; q < BLK; ++q) {
            const int i0 = (b * BLK + q) * 2;
            const float2 v0 = *(const float2*)(s0 + i0);
            const float2 v1 = *(const float2*)(s1 + i0);
            fma2(az[0], bz[cur][q], v0.x, v0.y); fma2(az[1], bz[cur][q], v1.x, v1.y);
            fma2(ar[0], br[cur][q], v0.x, v0.y); fma2(ar[1], br[cur][q], v1.x, v1.y);
            fma2(a3[0], bh[cur][q], v0.x, v0.y); fma2(a3[1], bh[cur][q], v1.x, v1.y);
        }
    }
}

// Single-row segment
template <int COLS, int NPAIRS>
__device__ __forceinline__ void gru_seg1(const __half2* __restrict__ pz,
                                         const __half2* __restrict__ pr,
                                         const __half2* __restrict__ ph,
                                         const float* __restrict__ s0,
                                         float& az, float& ar, float& a3)
{
    constexpr int NB = NPAIRS / BLK;
    __half2 bz[2][BLK], br[2][BLK], bh[2][BLK];
    #pragma unroll
    for (int q = 0; q < BLK; ++q) {
        bz[0][q] = pz[q * COLS]; br[0][q] = pr[q * COLS]; bh[0][q] = ph[q * COLS];
    }
    #pragma unroll 2
    for (int b = 0; b < NB; ++b) {
        const int cur = b & 1, nxt = cur ^ 1;
        if (b + 1 < NB) {
            const __half2* z2 = pz + (b + 1) * BLK * COLS;
            const __half2* r2 = pr + (b + 1) * BLK * COLS;
            const __half2* h2 = ph + (b + 1) * BLK * COLS;
            #pragma unroll
            for (int q = 0; q < BLK; ++q) {
                bz[nxt][q] = z2[q * COLS]; br[nxt][q] = r2[q * COLS]; bh[nxt][q] = h2[q * COLS];
            }
        }
        #pragma unroll
        for (int q = 0; q < BLK; ++q) {
            const int i0 = (b * BLK + q) * 2;
            const float2 v0 = *(const float2*)(s0 + i0);
            fma2(az, bz[cur][q], v0.x, v0.y);
            fma2(ar, br[cur][q], v0.x, v0.y);
            fma2(a3, bh[cur][q], v0.x, v0.y);
        }
    }
}

// 512 threads: col j = tid&255, K-half hf = tid>>8. 2 waves/SIMD.
__global__ __launch_bounds__(512, 2)
void gru_fused(const float* __restrict__ x,
               const float* __restrict__ b1, const float* __restrict__ b2,
               const float* __restrict__ w3, const float* __restrict__ b3,
               const float* __restrict__ w4, const float* __restrict__ b4,
               const float* __restrict__ w5, const float* __restrict__ b5,
               const __half2* __restrict__ wp,
               float* __restrict__ out)
{
    __shared__ float h1[ROWS][NU1];
    __shared__ float h2[ROWS][NU2];
    __shared__ float xt[2][ROWS][FEAT];
    __shared__ float red1[6][256];
    __shared__ float red2[4][256];
    __shared__ float d3[ROWS][64];
    __shared__ float d4[ROWS][32];

    const int tid  = threadIdx.x;
    const int j    = tid & 255;     // output column (GRU1 unit)
    const int hf   = tid >> 8;      // K-half
    const int row0 = blockIdx.x * ROWS;
    const int u2   = j & 127;       // GRU2 unit
    const int rr   = j >> 7;        // GRU2 batch row

    for (int i = tid; i < ROWS * NU1; i += 512) (&h1[0][0])[i] = 0.0f;
    for (int i = tid; i < ROWS * NU2; i += 512) (&h2[0][0])[i] = 0.0f;

    // biases only on the combining half (hf==0)
    float bz1 = 0, br1 = 0, bxh1 = 0, brh1 = 0;
    float bz2 = 0, br2 = 0, bxh2 = 0, brh2 = 0;
    if (hf == 0) {
        bz1  = b1[j] + b1[768 + j];
        br1  = b1[256 + j] + b1[1024 + j];
        bxh1 = b1[512 + j];
        brh1 = b1[1280 + j];
        bz2  = b2[u2] + b2[384 + u2];
        br2  = b2[128 + u2] + b2[512 + u2];
        bxh2 = b2[256 + u2];
        brh2 = b2[640 + u2];
    }

    const __half2* g1z = wp + G1Z_OFF + j;
    const __half2* g1r = wp + G1R_OFF + j;
    const __half2* g1h = wp + G1H_OFF + j;
    const __half2* g2z = wp + G2Z_OFF + u2;
    const __half2* g2r = wp + G2R_OFF + u2;
    const __half2* g2h = wp + G2H_OFF + u2;

    const int pr_ = tid >> 6, pf = tid & 63;   // x-stager (tid<128)
    if (tid < ROWS * FEAT)
        xt[0][pr_][pf] = x[((size_t)(row0 + pr_) * TSEQ) * FEAT + pf];
    __syncthreads();

    for (int t = 0; t < TSEQ; ++t) {
        const int cur = t & 1, nxt = cur ^ 1;

        float xpre = 0.0f;
        if (t + 1 < TSEQ && tid < ROWS * FEAT)
            xpre = x[((size_t)(row0 + pr_) * TSEQ + (t + 1)) * FEAT + pf];

        // ---------------- GRU1: K-half partials ----------------
        float az[2]  = {bz1, bz1},  ar[2]  = {br1, br1};
        float axh[2] = {bxh1, bxh1}, arh[2] = {brh1, brh1};
        if (hf == 0) {
            // pairs 0..31: x-part -> axh
            gru_seg2<256, 32>(g1z, g1r, g1h, &xt[cur][0][0], &xt[cur][1][0], az, ar, axh);
            // pairs 32..79: h1 rows 0..95 -> arh
            gru_seg2<256, 48>(g1z + 32 * 256, g1r + 32 * 256, g1h + 32 * 256,
                              &h1[0][0], &h1[1][0], az, ar, arh);
        } else {
            // pairs 80..159: h1 rows 96..255 -> arh
            gru_seg2<256, 80>(g1z + 80 * 256, g1r + 80 * 256, g1h + 80 * 256,
                              &h1[0][96], &h1[1][96], az, ar, arh);
        }
        if (hf == 1) {
            red1[0][j] = az[0];  red1[1][j] = az[1];
            red1[2][j] = ar[0];  red1[3][j] = ar[1];
            red1[4][j] = arh[0]; red1[5][j] = arh[1];
        }
        __syncthreads();   // (A) partials stored; all reads of old h1/xt done
        if (hf == 0) {
            az[0]  += red1[0][j]; az[1]  += red1[1][j];
            ar[0]  += red1[2][j]; ar[1]  += red1[3][j];
            arh[0] += red1[4][j]; arh[1] += red1[5][j];
            #pragma unroll
            for (int r = 0; r < 2; ++r) {
                const float z  = sigmoid_f(az[r]);
                const float rg = sigmoid_f(ar[r]);
                const float hh = tanh_f(axh[r] + rg * arh[r]);
                h1[r][j] = z * h1[r][j] + (1.0f - z) * hh;
            }
        }
        if (t + 1 < TSEQ && tid < ROWS * FEAT) xt[nxt][pr_][pf] = xpre;
        __syncthreads();   // (B) new h1 + next x visible

        // ---------------- GRU2: K-half partials ----------------
        float az2 = bz2, ar2 = br2, axh2 = bxh2, arh2 = brh2;
        if (hf == 0) {
            // pairs 0..95: h1 rows 0..191 -> axh2
            gru_seg1<128, 96>(g2z, g2r, g2h, &h1[rr][0], az2, ar2, axh2);
        } else {
            // pairs 96..127: h1 rows 192..255 -> axh2
            gru_seg1<128, 32>(g2z + 96 * 128, g2r + 96 * 128, g2h + 96 * 128,
                              &h1[rr][192], az2, ar2, axh2);
            // pairs 128..191: h2 rows 0..127 -> arh2
            gru_seg1<128, 64>(g2z + 128 * 128, g2r + 128 * 128, g2h + 128 * 128,
                              &h2[rr][0], az2, ar2, arh2);
        }
        if (hf == 1) {
            red2[0][j] = az2; red2[1][j] = ar2;
            red2[2][j] = axh2; red2[3][j] = arh2;
        }
        __syncthreads();   // (C) partials stored; all reads of old h2 done
        if (hf == 0) {
            az2  += red2[0][j]; ar2  += red2[1][j];
            axh2 += red2[2][j]; arh2 += red2[3][j];
            const float z2v = sigmoid_f(az2);
            const float rg2 = sigmoid_f(ar2);
            const float hh2 = tanh_f(axh2 + rg2 * arh2);
            h2[rr][u2] = z2v * h2[rr][u2] + (1.0f - z2v) * hh2;
        }
        __syncthreads();   // (D) new h2 visible
    }

    // ---------------- dense head: h2 -> 64 -> 32 -> 24 ----------------
    if (tid < ROWS * 64) {
        const int r = tid >> 6, jj = tid & 63;
        float a = b3[jj];
        #pragma unroll 4
        for (int u = 0; u < NU2; ++u) a += h2[r][u] * w3[u * 64 + jj];
        d3[r][jj] = a;
    }
    __syncthreads();
    if (tid < ROWS * 32) {
        const int r = tid >> 5, jj = tid & 31;
        float a = b4[jj];
        #pragma unroll 4
        for (int u = 0; u < 64; ++u) a += d3[r][u] * w4[u * 32 + jj];
        d4[r][jj] = a;
    }
    __syncthreads();
    if (tid < ROWS * 32) {
        const int r = tid >> 5, jj = tid & 31;
        if (jj < 24) {
            float a = b5[jj];
            #pragma unroll 4
            for (int u = 0; u < 32; ++u) a += d4[r][u] * w5[u * 24 + jj];
            out[(size_t)(row0 + r) * 24 + jj] = a;
        }
    }
}

extern "C" void kernel_launch(void* const* d_in, const int* in_sizes, int n_in,
                              void* d_out, int out_size, void* d_ws, size_t ws_size,
                              hipStream_t stream) {
    (void)in_sizes; (void)n_in; (void)ws_size; (void)out_size;
    const float* x  = (const float*)d_in[0];
    const float* k1 = (const float*)d_in[1];
    const float* r1 = (const float*)d_in[2];
    const float* b1 = (const float*)d_in[3];
    const float* k2 = (const float*)d_in[4];
    const float* r2 = (const float*)d_in[5];
    const float* b2 = (const float*)d_in[6];
    const float* w3 = (const float*)d_in[7];
    const float* b3 = (const float*)d_in[8];
    const float* w4 = (const float*)d_in[9];
    const float* b4 = (const float*)d_in[10];
    const float* w5 = (const float*)d_in[11];
    const float* b5 = (const float*)d_in[12];
    float* out = (float*)d_out;
    __half2* wp = (__half2*)d_ws;

    hipLaunchKernelGGL(pack_weights, dim3((TOTAL_H2 + 255) / 256), dim3(256), 0, stream,
                       k1, r1, k2, r2, wp);
    hipLaunchKernelGGL(gru_fused, dim3(BATCH / ROWS), dim3(512), 0, stream,
                       x, b1, b2, w3, b3, w4, b4, w5, b5, wp, out);
}

// Round 5
// 7144.138 us; speedup vs baseline: 3.2939x; 1.3426x over previous
//
#include <hip/hip_runtime.h>
#include <hip/hip_fp16.h>
#include <math.h>

// Problem constants
#define BATCH 256
#define TSEQ  512
#define FEAT  64
#define NU1   256
#define NU2   128
#define BLK   8      // pairs per pipeline block (24 outstanding 4B loads)

// half2-element offsets inside workspace (packed fp16 weight planes)
// Pair-plane layout (R2-proven, L2-resident): plane[pair][col], half2=(row0,row0+1).
// GRU1: 160 pairs (64 x-rows then 256 h-rows) x 256 cols, per gate.
// GRU2: 192 pairs (256 h1-rows then 128 h2-rows) x 128 cols, per gate.
#define G1Z_OFF 0
#define G1R_OFF 40960
#define G1H_OFF 81920
#define G2Z_OFF 122880
#define G2R_OFF 147456
#define G2H_OFF 172032
#define TOTAL_H2 196608   // 786,432 bytes of d_ws

__device__ __forceinline__ float sigmoid_f(float v) {
    return 1.0f / (1.0f + __expf(-v));
}
__device__ __forceinline__ float tanh_f(float v) {
    float c = fminf(fmaxf(v, -15.0f), 15.0f);
    float e = __expf(2.0f * c);
    return (e - 1.0f) / (e + 1.0f);
}

// ---------------- weight packing (fp32 -> fp16 pair planes) ----------------
__global__ void pack_weights(const float* __restrict__ k1, const float* __restrict__ r1,
                             const float* __restrict__ k2, const float* __restrict__ r2,
                             __half2* __restrict__ ws)
{
    int idx = blockIdx.x * 256 + threadIdx.x;
    if (idx >= TOTAL_H2) return;
    float a, b;
    if (idx < G2Z_OFF) {
        // GRU1 planes: 3 x [160 pairs][256 cols]
        int plane = idx / 40960;       // 0=z 1=r 2=h
        int rem   = idx % 40960;
        int pair  = rem >> 8;
        int col   = rem & 255;
        int g     = plane * 256 + col; // gate-column in [0,768)
        int row0  = pair * 2;
        if (row0 < 64) { a = k1[row0 * 768 + g];        b = k1[(row0 + 1) * 768 + g]; }
        else           { a = r1[(row0 - 64) * 768 + g]; b = r1[(row0 - 63) * 768 + g]; }
    } else {
        // GRU2 planes: 3 x [192 pairs][128 cols]
        int idx2  = idx - G2Z_OFF;
        int plane = idx2 / 24576;
        int rem   = idx2 % 24576;
        int pair  = rem >> 7;
        int col   = rem & 127;
        int g     = plane * 128 + col; // gate-column in [0,384)
        int row0  = pair * 2;
        if (row0 < 256) { a = k2[row0 * 384 + g];         b = k2[(row0 + 1) * 384 + g]; }
        else            { a = r2[(row0 - 256) * 384 + g]; b = r2[(row0 - 255) * 384 + g]; }
    }
    __half2 h;
    h.x = __float2half_rn(a);
    h.y = __float2half_rn(b);
    ws[idx] = h;
}

// acc += w.lo * x0 + w.hi * x1   (fp16 weight, fp32 data/accum; cvt is exact)
__device__ __forceinline__ void fma2(float& acc, __half2 w, float x0, float x1) {
    acc = fmaf(__half2float(__low2half(w)),  x0, acc);
    acc = fmaf(__half2float(__high2half(w)), x1, acc);
}

// K-segment over NPAIRS pairs: 3 gate streams, double-buffered register pipeline.
template <int COLS, int NPAIRS>
__device__ __forceinline__ void seg(const __half2* __restrict__ pz,
                                    const __half2* __restrict__ pr,
                                    const __half2* __restrict__ ph,
                                    const float* __restrict__ s0,
                                    float& az, float& ar, float& a3)
{
    constexpr int NB = NPAIRS / BLK;
    __half2 bz[2][BLK], br[2][BLK], bh[2][BLK];
    #pragma unroll
    for (int q = 0; q < BLK; ++q) {
        bz[0][q] = pz[q * COLS]; br[0][q] = pr[q * COLS]; bh[0][q] = ph[q * COLS];
    }
    #pragma unroll 2
    for (int b = 0; b < NB; ++b) {
        const int cur = b & 1, nxt = cur ^ 1;
        if (b + 1 < NB) {
            const __half2* z2 = pz + (b + 1) * BLK * COLS;
            const __half2* r2 = pr + (b + 1) * BLK * COLS;
            const __half2* h2 = ph + (b + 1) * BLK * COLS;
            #pragma unroll
            for (int q = 0; q < BLK; ++q) {
                bz[nxt][q] = z2[q * COLS]; br[nxt][q] = r2[q * COLS]; bh[nxt][q] = h2[q * COLS];
            }
        }
        #pragma unroll
        for (int q = 0; q < BLK; ++q) {
            const int i0 = (b * BLK + q) * 2;
            const float2 v0 = *(const float2*)(s0 + i0);
            fma2(az, bz[cur][q], v0.x, v0.y);
            fma2(ar, br[cur][q], v0.x, v0.y);
            fma2(a3, bh[cur][q], v0.x, v0.y);
        }
    }
}

// 256 WGs x 256 threads, one batch row per WG. One barrier per timestep.
__global__ __launch_bounds__(256, 2)
void gru_fused(const float* __restrict__ x,
               const float* __restrict__ b1, const float* __restrict__ b2,
               const float* __restrict__ w3, const float* __restrict__ b3,
               const float* __restrict__ w4, const float* __restrict__ b4,
               const float* __restrict__ w5, const float* __restrict__ b5,
               const __half2* __restrict__ wp,
               float* __restrict__ out)
{
    __shared__ float h1[2][NU1];   // double-buffered
    __shared__ float h2[2][NU2];   // double-buffered
    __shared__ float xt[2][FEAT];  // double-buffered
    __shared__ float d3[64];
    __shared__ float d4[32];

    const int tid = threadIdx.x;
    const int row = blockIdx.x;
    const int j   = tid;            // GRU1 column
    const int c2  = tid >> 1;       // GRU2 column
    const int kh  = tid & 1;        // GRU2 K-half (uniform code path, ptr offsets only)

    for (int i = tid; i < 2 * NU1; i += 256) (&h1[0][0])[i] = 0.0f;
    for (int i = tid; i < 2 * NU2; i += 256) (&h2[0][0])[i] = 0.0f;

    // GRU1 biases (z,r folded; h kept split for reset_after)
    const float bz1  = b1[j] + b1[768 + j];
    const float br1  = b1[256 + j] + b1[1024 + j];
    const float bxh1 = b1[512 + j];
    const float brh1 = b1[1280 + j];
    // GRU2 biases, masked to even lane (kh==0) so the shfl-sum counts them once
    const float bm   = (kh == 0) ? 1.0f : 0.0f;
    const float bz2  = (b2[c2] + b2[384 + c2]) * bm;
    const float br2  = (b2[128 + c2] + b2[512 + c2]) * bm;
    const float bxh2 = b2[256 + c2] * bm;
    const float brh2 = b2[640 + c2] * bm;

    const __half2* g1z = wp + G1Z_OFF + j;
    const __half2* g1r = wp + G1R_OFF + j;
    const __half2* g1h = wp + G1H_OFF + j;
    // GRU2 K-split: kh half of h1-part (64 pairs) + kh half of h2-part (32 pairs)
    const __half2* g2z_a = wp + G2Z_OFF + kh * 64 * 128 + c2;
    const __half2* g2r_a = wp + G2R_OFF + kh * 64 * 128 + c2;
    const __half2* g2h_a = wp + G2H_OFF + kh * 64 * 128 + c2;
    const __half2* g2z_b = wp + G2Z_OFF + (128 + kh * 32) * 128 + c2;
    const __half2* g2r_b = wp + G2R_OFF + (128 + kh * 32) * 128 + c2;
    const __half2* g2h_b = wp + G2H_OFF + (128 + kh * 32) * 128 + c2;

    if (tid < FEAT)
        xt[0][tid] = x[(size_t)row * TSEQ * FEAT + tid];
    __syncthreads();

    for (int t = 0; t < TSEQ; ++t) {
        const int cur = t & 1, nb = cur ^ 1;

        // prefetch next x into registers (stored to LDS before the barrier)
        float xpre = 0.0f;
        if (t + 1 < TSEQ && tid < FEAT)
            xpre = x[(size_t)row * TSEQ * FEAT + (t + 1) * FEAT + tid];

        // ---------------- GRU1: reads h1[cur], xt[cur]; writes h1[nb] ----------------
        float az = bz1, ar = br1, axh = bxh1, arh = brh1;
        seg<256, 32>(g1z, g1r, g1h, &xt[cur][0], az, ar, axh);
        seg<256, 128>(g1z + 32 * 256, g1r + 32 * 256, g1h + 32 * 256,
                      &h1[cur][0], az, ar, arh);
        {
            const float z  = sigmoid_f(az);
            const float rg = sigmoid_f(ar);
            const float hh = tanh_f(axh + rg * arh);
            h1[nb][j] = z * h1[cur][j] + (1.0f - z) * hh;
        }
        if (t + 1 < TSEQ && tid < FEAT) xt[nb][tid] = xpre;
        __syncthreads();   // THE one barrier: h1[nb] + xt[nb] visible to all

        // ---------------- GRU2: reads h1[nb], h2[cur]; writes h2[nb] ----------------
        float az2 = bz2, ar2 = br2, axh2 = bxh2, arh2 = brh2;
        seg<128, 64>(g2z_a, g2r_a, g2h_a, &h1[nb][kh * 128], az2, ar2, axh2);
        seg<128, 32>(g2z_b, g2r_b, g2h_b, &h2[cur][kh * 64], az2, ar2, arh2);
        // intra-wave pair reduction (lanes 2c / 2c+1)
        az2  += __shfl_xor(az2, 1);
        ar2  += __shfl_xor(ar2, 1);
        axh2 += __shfl_xor(axh2, 1);
        arh2 += __shfl_xor(arh2, 1);
        {
            const float z2v = sigmoid_f(az2);
            const float rg2 = sigmoid_f(ar2);
            const float hh2 = tanh_f(axh2 + rg2 * arh2);
            const float hn2 = z2v * h2[cur][c2] + (1.0f - z2v) * hh2;
            if (kh == 0) h2[nb][c2] = hn2;
        }
        // no second barrier: next step's barrier covers h2[nb]/xt visibility;
        // all WAR hazards are buffer-separated (see analysis)
    }
    __syncthreads();   // h2[0] (written at t=511) visible for the head

    // ---------------- dense head: h2[0] -> 64 -> 32 -> 24 ----------------
    if (tid < 64) {
        float a = b3[tid];
        #pragma unroll 4
        for (int u = 0; u < NU2; ++u) a += h2[0][u] * w3[u * 64 + tid];
        d3[tid] = a;
    }
    __syncthreads();
    if (tid < 32) {
        float a = b4[tid];
        #pragma unroll 4
        for (int u = 0; u < 64; ++u) a += d3[u] * w4[u * 32 + tid];
        d4[tid] = a;
    }
    __syncthreads();
    if (tid < 24) {
        float a = b5[tid];
        #pragma unroll 4
        for (int u = 0; u < 32; ++u) a += d4[u] * w5[u * 24 + tid];
        out[(size_t)row * 24 + tid] = a;
    }
}

extern "C" void kernel_launch(void* const* d_in, const int* in_sizes, int n_in,
                              void* d_out, int out_size, void* d_ws, size_t ws_size,
                              hipStream_t stream) {
    (void)in_sizes; (void)n_in; (void)ws_size; (void)out_size;
    const float* x  = (const float*)d_in[0];
    const float* k1 = (const float*)d_in[1];
    const float* r1 = (const float*)d_in[2];
    const float* b1 = (const float*)d_in[3];
    const float* k2 = (const float*)d_in[4];
    const float* r2 = (const float*)d_in[5];
    const float* b2 = (const float*)d_in[6];
    const float* w3 = (const float*)d_in[7];
    const float* b3 = (const float*)d_in[8];
    const float* w4 = (const float*)d_in[9];
    const float* b4 = (const float*)d_in[10];
    const float* w5 = (const float*)d_in[11];
    const float* b5 = (const float*)d_in[12];
    float* out = (float*)d_out;
    __half2* wp = (__half2*)d_ws;

    hipLaunchKernelGGL(pack_weights, dim3((TOTAL_H2 + 255) / 256), dim3(256), 0, stream,
                       k1, r1, k2, r2, wp);
    hipLaunchKernelGGL(gru_fused, dim3(BATCH), dim3(256), 0, stream,
                       x, b1, b2, w3, b3, w4, b4, w5, b5, wp, out);
}